// Round 1
// baseline (14575.433 us; speedup 1.0000x reference)
//
#include <hip/hip_runtime.h>
#include <hip/hip_bf16.h>
#include <math.h>

#define VSZ 1056
#define DD 320
#define NH 5
#define HD 64
#define FF 864
#define NL 6
#define NLOOPS 8
#define BB 8
#define SL 2048
#define KK 1638          // int(2048 * 0.8)
#define EPSF 1e-6f

// ======================= embed =======================
__global__ __launch_bounds__(256) void embed_kernel(const int* __restrict__ ids,
        const int* __restrict__ iter, const float* __restrict__ emb,
        const float* __restrict__ iter_emb, float* __restrict__ x) {
    int i = blockIdx.x * 256 + threadIdx.x;          // over B*S*D
    int d = i % DD, bs = i / DD;
    float v = emb[(size_t)ids[bs] * DD + d];
    int it = iter[0];
    if (it < NLOOPS) v += iter_emb[it * DD + d];
    x[i] = v;
}

// ======================= rmsnorm (1 wave per row, D=320 -> 5/lane) =======================
__global__ __launch_bounds__(256) void rmsnorm_kernel(const float* __restrict__ x,
        const float* __restrict__ w, float* __restrict__ out, int nrows) {
    int row = blockIdx.x * 4 + (threadIdx.x >> 6);
    int lane = threadIdx.x & 63;
    if (row >= nrows) return;
    const float* xr = x + (size_t)row * DD;
    float v[5]; float ss = 0.f;
#pragma unroll
    for (int i = 0; i < 5; ++i) { v[i] = xr[lane + i * 64]; ss += v[i] * v[i]; }
#pragma unroll
    for (int o = 32; o > 0; o >>= 1) ss += __shfl_xor(ss, o);
    float r = rsqrtf(ss * (1.f / DD) + EPSF);
    float* orow = out + (size_t)row * DD;
#pragma unroll
    for (int i = 0; i < 5; ++i) orow[lane + i * 64] = w[lane + i * 64] * v[i] * r;
}

// gather selected tokens + rmsnorm
__global__ __launch_bounds__(256) void gather_rmsnorm_kernel(const float* __restrict__ x,
        const int* __restrict__ tkidx, const float* __restrict__ w,
        float* __restrict__ out, int nrows) {
    int row = blockIdx.x * 4 + (threadIdx.x >> 6);
    int lane = threadIdx.x & 63;
    if (row >= nrows) return;
    int b = row / KK;
    int t = tkidx[row];
    const float* xr = x + ((size_t)b * SL + t) * DD;
    float v[5]; float ss = 0.f;
#pragma unroll
    for (int i = 0; i < 5; ++i) { v[i] = xr[lane + i * 64]; ss += v[i] * v[i]; }
#pragma unroll
    for (int o = 32; o > 0; o >>= 1) ss += __shfl_xor(ss, o);
    float r = rsqrtf(ss * (1.f / DD) + EPSF);
    float* orow = out + (size_t)row * DD;
#pragma unroll
    for (int i = 0; i < 5; ++i) orow[lane + i * 64] = w[lane + i * 64] * v[i] * r;
}

// ======================= router: sigmoid(x . rw) =======================
__global__ __launch_bounds__(256) void router_kernel(const float* __restrict__ x,
        const float* __restrict__ rw, float* __restrict__ probs, int nrows) {
    int row = blockIdx.x * 4 + (threadIdx.x >> 6);
    int lane = threadIdx.x & 63;
    if (row >= nrows) return;
    const float* xr = x + (size_t)row * DD;
    float ss = 0.f;
#pragma unroll
    for (int i = 0; i < 5; ++i) ss += xr[lane + i * 64] * rw[lane + i * 64];
#pragma unroll
    for (int o = 32; o > 0; o >>= 1) ss += __shfl_xor(ss, o);
    if (lane == 0) probs[row] = 1.f / (1.f + __expf(-ss));
}

// ======================= top-k: exact bitonic sort (desc value, asc index) =======================
__global__ __launch_bounds__(1024) void topk_kernel(const float* __restrict__ probs,
        int* __restrict__ tkidx, float* __restrict__ tkprob) {
    __shared__ unsigned long long keys[SL];
    int b = blockIdx.x, tid = threadIdx.x;
    for (int i = tid; i < SL; i += 1024) {
        unsigned int fb = __float_as_uint(probs[b * SL + i]);  // sigmoid > 0 -> bits monotonic
        keys[i] = ((unsigned long long)fb << 32) | (unsigned int)(SL - 1 - i);
    }
    __syncthreads();
    for (int k = 2; k <= SL; k <<= 1) {
        for (int j = k >> 1; j > 0; j >>= 1) {
            for (int i = tid; i < SL; i += 1024) {
                int ixj = i ^ j;
                if (ixj > i) {
                    unsigned long long a = keys[i], c = keys[ixj];
                    bool up = ((i & k) == 0);   // descending overall
                    if (up ? (a < c) : (a > c)) { keys[i] = c; keys[ixj] = a; }
                }
            }
            __syncthreads();
        }
    }
    for (int i = tid; i < KK; i += 1024) {
        unsigned long long key = keys[i];
        tkidx[b * KK + i] = (SL - 1) - (int)(key & 0xffffffffu);
        tkprob[b * KK + i] = __uint_as_float((unsigned int)(key >> 32));
    }
}

// ======================= RoPE (in-place on q,k of qkv) =======================
__global__ __launch_bounds__(256) void rope_kernel(float* __restrict__ qkv) {
    int i = blockIdx.x * 256 + threadIdx.x;          // over B*S*2*NH*32
    int dd = i & 31; int r = i >> 5;
    int h = r % NH; r /= NH;
    int qk = r & 1; r >>= 1;
    int s = r % SL; int b = r / SL;
    float freq = exp2f(-(float)dd * 0.4152410118609203f);   // 10000^(-dd/32)
    float ang = (float)s * freq;
    float c = cosf(ang), sn = sinf(ang);
    size_t base = ((((size_t)(b * SL + s) * 3 + qk) * NH + h) << 6);
    float x1 = qkv[base + dd], x2 = qkv[base + dd + 32];
    qkv[base + dd]      = x1 * c - x2 * sn;
    qkv[base + dd + 32] = x2 * c + x1 * sn;
}

// ======================= attention: 1 q-row per wave, online softmax =======================
// Kt: [d4][j] float4, row stride 260 words (16B aligned, 2-way banks = free)
// Vt: [d][j],  row stride 68 words
__global__ __launch_bounds__(256) void attn_kernel(const float* __restrict__ qkv,
        float* __restrict__ out) {
    __shared__ float Kt[16 * 260];
    __shared__ float Vt[64 * 68];
    __shared__ float qs[4 * 64];
    __shared__ float ps[4 * 64];
    int tid = threadIdx.x;
    int lane = tid & 63, wave = tid >> 6;
    int bx = blockIdx.x, h = blockIdx.y, b = blockIdx.z;
    int q = bx * 4 + wave;
    qs[wave * 64 + lane] = qkv[(((size_t)(b * SL + q) * 3 + 0) * NH + h) * 64 + lane] * 0.125f;
    float m = -INFINITY, l = 0.f, acc = 0.f;        // acc: dim = lane
    int qmax = bx * 4 + 3;
    int ntiles = qmax / 64 + 1;
    for (int t = 0; t < ntiles; ++t) {
        int j0 = t * 64;
        __syncthreads();
#pragma unroll
        for (int p = 0; p < 4; ++p) {
            int i = p * 256 + tid;                   // j = i>>4 (coalesced), d4 = i&15
            int j = i >> 4, d4 = i & 15;
            size_t rbase = (size_t)(b * SL + j0 + j) * 3;
            const float4 kv = *(const float4*)(qkv + ((rbase + 1) * NH + h) * 64 + d4 * 4);
            float* kd = &Kt[d4 * 260 + 4 * j];
            kd[0] = kv.x; kd[1] = kv.y; kd[2] = kv.z; kd[3] = kv.w;
            const float4 vv = *(const float4*)(qkv + ((rbase + 2) * NH + h) * 64 + d4 * 4);
            Vt[(d4 * 4 + 0) * 68 + j] = vv.x; Vt[(d4 * 4 + 1) * 68 + j] = vv.y;
            Vt[(d4 * 4 + 2) * 68 + j] = vv.z; Vt[(d4 * 4 + 3) * 68 + j] = vv.w;
        }
        __syncthreads();
        // scores: this lane owns key j = j0 + lane
        float sc = 0.f;
        const float* qrow = &qs[wave * 64];
#pragma unroll
        for (int d4 = 0; d4 < 16; ++d4) {
            float4 q4 = *(const float4*)(qrow + d4 * 4);     // broadcast
            const float* kp = &Kt[d4 * 260 + 4 * lane];
            sc += q4.x * kp[0] + q4.y * kp[1] + q4.z * kp[2] + q4.w * kp[3];
        }
        if (j0 + lane > q) sc = -INFINITY;
        float tmax = sc;
#pragma unroll
        for (int o = 32; o > 0; o >>= 1) tmax = fmaxf(tmax, __shfl_xor(tmax, o));
        float mnew = fmaxf(m, tmax);
        float p = __expf(sc - mnew);                 // exp(-inf) = 0
        float alpha = (m == -INFINITY) ? 0.f : __expf(m - mnew);
        float psum = p;
#pragma unroll
        for (int o = 32; o > 0; o >>= 1) psum += __shfl_xor(psum, o);
        l = l * alpha + psum;
        m = mnew;
        ps[wave * 64 + lane] = p;
        acc *= alpha;
        const float* pw = &ps[wave * 64];
#pragma unroll
        for (int j4 = 0; j4 < 16; ++j4) {
            float4 p4 = *(const float4*)(pw + j4 * 4);       // broadcast
            const float* vp = &Vt[lane * 68 + j4 * 4];
            acc += p4.x * vp[0] + p4.y * vp[1] + p4.z * vp[2] + p4.w * vp[3];
        }
    }
    out[((size_t)(b * SL + q) * NH + h) * 64 + lane] = acc / l;
}

// ======================= generic tiled GEMM: C[M,N] = A[M,K] @ W[N,K]^T =======================
// MODE 0: C = acc          MODE 1: C += acc
// MODE 2: x[(b*SL + sidx[m])*N + n] += acc * sprob[m]   (m -> b = m/KK)
// MODE 3: C = silu(C) * acc
template<int MODE>
__global__ __launch_bounds__(256) void gemm_bt(const float* __restrict__ A,
        const float* __restrict__ W, float* __restrict__ C, int M, int N, int K,
        const int* __restrict__ sidx, const float* __restrict__ sprob) {
    __shared__ float As[16][65];
    __shared__ float Ws[16][65];
    int tid = threadIdx.x;
    int tx = tid & 15, ty = tid >> 4;
    int m0 = blockIdx.y * 64, n0 = blockIdx.x * 64;
    int lrow = tid >> 2;
    int lk = (tid & 3) * 4;
    float acc[4][4] = {};
    for (int k0 = 0; k0 < K; k0 += 16) {
        float4 av = make_float4(0.f, 0.f, 0.f, 0.f), wv = make_float4(0.f, 0.f, 0.f, 0.f);
        if (m0 + lrow < M) av = *(const float4*)(A + (size_t)(m0 + lrow) * K + k0 + lk);
        if (n0 + lrow < N) wv = *(const float4*)(W + (size_t)(n0 + lrow) * K + k0 + lk);
        __syncthreads();
        As[lk + 0][lrow] = av.x; As[lk + 1][lrow] = av.y; As[lk + 2][lrow] = av.z; As[lk + 3][lrow] = av.w;
        Ws[lk + 0][lrow] = wv.x; Ws[lk + 1][lrow] = wv.y; Ws[lk + 2][lrow] = wv.z; Ws[lk + 3][lrow] = wv.w;
        __syncthreads();
#pragma unroll
        for (int k = 0; k < 16; ++k) {
            float a[4], w4[4];
#pragma unroll
            for (int i = 0; i < 4; ++i) a[i] = As[k][ty * 4 + i];
#pragma unroll
            for (int j = 0; j < 4; ++j) w4[j] = Ws[k][tx * 4 + j];
#pragma unroll
            for (int i = 0; i < 4; ++i)
#pragma unroll
                for (int j = 0; j < 4; ++j) acc[i][j] += a[i] * w4[j];
        }
    }
#pragma unroll
    for (int i = 0; i < 4; ++i) {
        int mm = m0 + ty * 4 + i;
        if (mm >= M) continue;
        float* crow;
        float scale = 1.f;
        if (MODE == 2) {
            int b = mm / KK;
            crow = C + ((size_t)(b * SL + sidx[mm])) * N;
            scale = sprob[mm];
        } else {
            crow = C + (size_t)mm * N;
        }
#pragma unroll
        for (int j = 0; j < 4; ++j) {
            int nn = n0 + tx * 4 + j;
            if (nn >= N) continue;
            if (MODE == 0) {
                crow[nn] = acc[i][j];
            } else if (MODE == 1) {
                crow[nn] += acc[i][j];
            } else if (MODE == 2) {
                crow[nn] += acc[i][j] * scale;
            } else {                                  // MODE 3: silu(gate) * up
                float c = crow[nn];
                crow[nn] = (c / (1.f + __expf(-c))) * acc[i][j];
            }
        }
    }
}

// ======================= launch =======================
extern "C" void kernel_launch(void* const* d_in, const int* in_sizes, int n_in,
                              void* d_out, int out_size, void* d_ws, size_t ws_size,
                              hipStream_t stream) {
    const int*   ids          = (const int*)d_in[0];
    const int*   iter         = (const int*)d_in[1];
    const float* emb          = (const float*)d_in[2];
    const float* iter_emb     = (const float*)d_in[3];
    const float* attn_norm_w  = (const float*)d_in[4];
    const float* Wqkv         = (const float*)d_in[5];
    const float* wo_w         = (const float*)d_in[6];
    const float* router_w     = (const float*)d_in[7];
    const float* mlp_norm_w   = (const float*)d_in[8];
    const float* gate_w       = (const float*)d_in[9];
    const float* up_w         = (const float*)d_in[10];
    const float* down_w       = (const float*)d_in[11];
    const float* final_norm_w = (const float*)d_in[12];
    float* out = (float*)d_out;

    const size_t XN   = (size_t)BB * SL * DD;        // 5,242,880
    const size_t QKVN = (size_t)BB * SL * 3 * DD;    // 15,728,640
    char* ws = (char*)d_ws;
    float* x        = (float*)(ws);
    float* h        = (float*)(ws + XN * 4);
    float* qkv      = (float*)(ws + 2 * XN * 4);      // also reused as g-buffer
    float* attn_out = (float*)(ws + 2 * XN * 4 + QKVN * 4);
    float* probs    = (float*)(ws + 3 * XN * 4 + QKVN * 4);
    int*   tkidx    = (int*)  (ws + 3 * XN * 4 + QKVN * 4 + 65536);
    float* tkprob   = (float*)(ws + 3 * XN * 4 + QKVN * 4 + 65536 + BB * KK * 4);
    float* g1       = qkv;                            // 45.3MB <= 62.9MB, qkv dead by then

    embed_kernel<<<20480, 256, 0, stream>>>(ids, iter, emb, iter_emb, x);

    for (int l = 0; l < NL; ++l) {
        rmsnorm_kernel<<<4096, 256, 0, stream>>>(x, attn_norm_w + l * DD, h, BB * SL);
        gemm_bt<0><<<dim3(15, 256), 256, 0, stream>>>(h, Wqkv + (size_t)l * 3 * DD * DD, qkv,
                                                      BB * SL, 3 * DD, DD, nullptr, nullptr);
        rope_kernel<<<20480, 256, 0, stream>>>(qkv);
        attn_kernel<<<dim3(SL / 4, NH, BB), 256, 0, stream>>>(qkv, attn_out);
        gemm_bt<1><<<dim3(5, 256), 256, 0, stream>>>(attn_out, wo_w + (size_t)l * DD * DD, x,
                                                     BB * SL, DD, DD, nullptr, nullptr);
        router_kernel<<<4096, 256, 0, stream>>>(x, router_w + l * DD, probs, BB * SL);
        topk_kernel<<<BB, 1024, 0, stream>>>(probs, tkidx, tkprob);
        gather_rmsnorm_kernel<<<3276, 256, 0, stream>>>(x, tkidx, mlp_norm_w + l * DD, h, BB * KK);
        gemm_bt<0><<<dim3(14, 205), 256, 0, stream>>>(h, gate_w + (size_t)l * FF * DD, g1,
                                                      BB * KK, FF, DD, nullptr, nullptr);
        gemm_bt<3><<<dim3(14, 205), 256, 0, stream>>>(h, up_w + (size_t)l * FF * DD, g1,
                                                      BB * KK, FF, DD, nullptr, nullptr);
        gemm_bt<2><<<dim3(5, 205), 256, 0, stream>>>(g1, down_w + (size_t)l * DD * FF, x,
                                                     BB * KK, DD, FF, tkidx, tkprob);
    }
    rmsnorm_kernel<<<4096, 256, 0, stream>>>(x, final_norm_w, out, BB * SL);
}

// Round 2
// 5734.180 us; speedup vs baseline: 2.5419x; 2.5419x over previous
//
#include <hip/hip_runtime.h>
#include <hip/hip_bf16.h>
#include <math.h>

#define VSZ 1056
#define DD 320
#define NH 5
#define HD 64
#define FF 864
#define NL 6
#define NLOOPS 8
#define BB 8
#define SL 2048
#define KK 1638          // int(2048 * 0.8)
#define EPSF 1e-6f

typedef __bf16 bf16x8 __attribute__((ext_vector_type(8)));
typedef float floatx16 __attribute__((ext_vector_type(16)));

// ======================= embed =======================
__global__ __launch_bounds__(256) void embed_kernel(const int* __restrict__ ids,
        const int* __restrict__ iter, const float* __restrict__ emb,
        const float* __restrict__ iter_emb, float* __restrict__ x) {
    int i = blockIdx.x * 256 + threadIdx.x;          // over B*S*D
    int d = i % DD, bs = i / DD;
    float v = emb[(size_t)ids[bs] * DD + d];
    int it = iter[0];
    if (it < NLOOPS) v += iter_emb[it * DD + d];
    x[i] = v;
}

// ======================= rmsnorm (1 wave per row, D=320 -> 5/lane) =======================
__global__ __launch_bounds__(256) void rmsnorm_kernel(const float* __restrict__ x,
        const float* __restrict__ w, float* __restrict__ out, int nrows) {
    int row = blockIdx.x * 4 + (threadIdx.x >> 6);
    int lane = threadIdx.x & 63;
    if (row >= nrows) return;
    const float* xr = x + (size_t)row * DD;
    float v[5]; float ss = 0.f;
#pragma unroll
    for (int i = 0; i < 5; ++i) { v[i] = xr[lane + i * 64]; ss += v[i] * v[i]; }
#pragma unroll
    for (int o = 32; o > 0; o >>= 1) ss += __shfl_xor(ss, o);
    float r = rsqrtf(ss * (1.f / DD) + EPSF);
    float* orow = out + (size_t)row * DD;
#pragma unroll
    for (int i = 0; i < 5; ++i) orow[lane + i * 64] = w[lane + i * 64] * v[i] * r;
}

// gather selected tokens + rmsnorm
__global__ __launch_bounds__(256) void gather_rmsnorm_kernel(const float* __restrict__ x,
        const int* __restrict__ tkidx, const float* __restrict__ w,
        float* __restrict__ out, int nrows) {
    int row = blockIdx.x * 4 + (threadIdx.x >> 6);
    int lane = threadIdx.x & 63;
    if (row >= nrows) return;
    int b = row / KK;
    int t = tkidx[row];
    const float* xr = x + ((size_t)b * SL + t) * DD;
    float v[5]; float ss = 0.f;
#pragma unroll
    for (int i = 0; i < 5; ++i) { v[i] = xr[lane + i * 64]; ss += v[i] * v[i]; }
#pragma unroll
    for (int o = 32; o > 0; o >>= 1) ss += __shfl_xor(ss, o);
    float r = rsqrtf(ss * (1.f / DD) + EPSF);
    float* orow = out + (size_t)row * DD;
#pragma unroll
    for (int i = 0; i < 5; ++i) orow[lane + i * 64] = w[lane + i * 64] * v[i] * r;
}

// ======================= router: sigmoid(x . rw) =======================
__global__ __launch_bounds__(256) void router_kernel(const float* __restrict__ x,
        const float* __restrict__ rw, float* __restrict__ probs, int nrows) {
    int row = blockIdx.x * 4 + (threadIdx.x >> 6);
    int lane = threadIdx.x & 63;
    if (row >= nrows) return;
    const float* xr = x + (size_t)row * DD;
    float ss = 0.f;
#pragma unroll
    for (int i = 0; i < 5; ++i) ss += xr[lane + i * 64] * rw[lane + i * 64];
#pragma unroll
    for (int o = 32; o > 0; o >>= 1) ss += __shfl_xor(ss, o);
    if (lane == 0) probs[row] = 1.f / (1.f + __expf(-ss));
}

// ======================= top-k: exact bitonic sort (desc value, asc index) =======================
__global__ __launch_bounds__(1024) void topk_kernel(const float* __restrict__ probs,
        int* __restrict__ tkidx, float* __restrict__ tkprob) {
    __shared__ unsigned long long keys[SL];
    int b = blockIdx.x, tid = threadIdx.x;
    for (int i = tid; i < SL; i += 1024) {
        unsigned int fb = __float_as_uint(probs[b * SL + i]);  // sigmoid > 0 -> bits monotonic
        keys[i] = ((unsigned long long)fb << 32) | (unsigned int)(SL - 1 - i);
    }
    __syncthreads();
    for (int k = 2; k <= SL; k <<= 1) {
        for (int j = k >> 1; j > 0; j >>= 1) {
            for (int i = tid; i < SL; i += 1024) {
                int ixj = i ^ j;
                if (ixj > i) {
                    unsigned long long a = keys[i], c = keys[ixj];
                    bool up = ((i & k) == 0);   // descending overall
                    if (up ? (a < c) : (a > c)) { keys[i] = c; keys[ixj] = a; }
                }
            }
            __syncthreads();
        }
    }
    for (int i = tid; i < KK; i += 1024) {
        unsigned long long key = keys[i];
        tkidx[b * KK + i] = (SL - 1) - (int)(key & 0xffffffffu);
        tkprob[b * KK + i] = __uint_as_float((unsigned int)(key >> 32));
    }
}

// ======================= prep: RoPE + cast bf16, Q scaled by 1/8, V transposed =======================
// qkv fp32 [b][s][3][NH][64] -> Qb [bh][s][64] (x0.125, roped), Kb [bh][s][64] (roped),
//                              Vb [bh][64][s]
__global__ __launch_bounds__(256) void prep_kernel(const float* __restrict__ qkv,
        __bf16* __restrict__ Qb, __bf16* __restrict__ Kb, __bf16* __restrict__ Vb) {
    __shared__ __bf16 vt[64][72];
    int tid = threadIdx.x;
    int s0 = blockIdx.x * 64, h = blockIdx.y, b = blockIdx.z;
    int bh = b * NH + h;
#pragma unroll
    for (int p = 0; p < 16; ++p) {
        int idx = p * 256 + tid;                 // 64 s x 64 d
        int sl = idx >> 6, d = idx & 63;
        int s = s0 + sl;
        size_t rbase = ((size_t)(b * SL + s) * 3) * (NH * 64) + h * 64;
        float qv = qkv[rbase + d], qp = qkv[rbase + (d ^ 32)];
        float kv = qkv[rbase + NH * 64 + d], kp = qkv[rbase + NH * 64 + (d ^ 32)];
        float vv = qkv[rbase + 2 * NH * 64 + d];
        float freq = exp2f(-(float)(d & 31) * 0.4152410118609203f);   // 10000^(-j/32)
        float ang = (float)s * freq;
        float c = cosf(ang), sn = sinf(ang);
        float qr = (d < 32) ? qv * c - qp * sn : qv * c + qp * sn;
        float kr = (d < 32) ? kv * c - kp * sn : kv * c + kp * sn;
        Qb[((size_t)bh * SL + s) * 64 + d] = (__bf16)(qr * 0.125f);
        Kb[((size_t)bh * SL + s) * 64 + d] = (__bf16)kr;
        vt[sl][d] = (__bf16)vv;
    }
    __syncthreads();
#pragma unroll
    for (int p = 0; p < 16; ++p) {
        int idx = p * 256 + tid;                 // 64 d x 64 s
        int d = idx >> 6, sl = idx & 63;
        Vb[((size_t)bh * 64 + d) * SL + s0 + sl] = vt[sl][d];
    }
}

// ======================= attention: MFMA 32x32x16 flash, S^T/O^T orientation =======================
__global__ __launch_bounds__(256) void attn_mfma(const __bf16* __restrict__ Qb,
        const __bf16* __restrict__ Kb, const __bf16* __restrict__ Vb,
        float* __restrict__ attn_out) {
    __shared__ __attribute__((aligned(16))) __bf16 kt[2048];   // 32 keys x 8 chunks x 8 (XOR swizzle)
    __shared__ __attribute__((aligned(16))) __bf16 vt[2048];   // 64 d    x 4 chunks x 8 (XOR swizzle)
    int tid = threadIdx.x;
    int wave = tid >> 6, lane = tid & 63;
    int l31 = lane & 31, h5 = lane >> 5;
    int bx = (int)(gridDim.x - 1) - (int)blockIdx.x;   // longest blocks first
    int h = blockIdx.y, b = blockIdx.z;
    int bh = b * NH + h;
    int qw = bx * 128 + wave * 32;
    int myq = qw + l31;

    bf16x8 qf[4];
    const __bf16* qrow = Qb + ((size_t)bh * SL + myq) * 64;
#pragma unroll
    for (int kd = 0; kd < 4; ++kd)
        qf[kd] = *(const bf16x8*)(qrow + kd * 16 + h5 * 8);

    floatx16 O0, O1;
#pragma unroll
    for (int r = 0; r < 16; ++r) { O0[r] = 0.f; O1[r] = 0.f; }
    float m = -INFINITY, l = 0.f;

    int ntiles = bx * 4 + 4;
    for (int t = 0; t < ntiles; ++t) {
        int t0 = t * 32;
        __syncthreads();
        {
            int key = tid >> 3, c = tid & 7;
            *(uint4*)(kt + key * 64 + ((c ^ (key & 7)) * 8)) =
                *(const uint4*)(Kb + ((size_t)bh * SL + t0 + key) * 64 + c * 8);
            int d = tid >> 2, c2 = tid & 3;
            *(uint4*)(vt + d * 32 + ((c2 ^ (d & 3)) * 8)) =
                *(const uint4*)(Vb + ((size_t)bh * 64 + d) * SL + t0 + c2 * 8);
        }
        __syncthreads();
        if (t0 > qw + 31) continue;              // wave-uniform; syncs stay aligned

        // S^T = K (A, m=key) x Q (B, n=q): C col = q = l31, row = key
        floatx16 S;
#pragma unroll
        for (int r = 0; r < 16; ++r) S[r] = 0.f;
#pragma unroll
        for (int kd = 0; kd < 4; ++kd) {
            bf16x8 af = *(const bf16x8*)(kt + l31 * 64 + (((kd * 2 + h5) ^ (l31 & 7)) * 8));
            S = __builtin_amdgcn_mfma_f32_32x32x16_bf16(af, qf[kd], S, 0, 0, 0);
        }
        if (t0 + 31 > qw) {                      // diagonal tile: causal mask
#pragma unroll
            for (int r = 0; r < 16; ++r) {
                int key = t0 + (r & 3) + 8 * (r >> 2) + 4 * h5;
                S[r] = (key > myq) ? -INFINITY : S[r];
            }
        }
        // online softmax over keys (rows): in-lane regs + cross-half shfl
        float tmax = S[0];
#pragma unroll
        for (int r = 1; r < 16; ++r) tmax = fmaxf(tmax, S[r]);
        tmax = fmaxf(tmax, __shfl_xor(tmax, 32));
        float mnew = fmaxf(m, tmax);
        float alpha = __expf(m - mnew);
        float P[16]; float psum = 0.f;
#pragma unroll
        for (int r = 0; r < 16; ++r) { P[r] = __expf(S[r] - mnew); psum += P[r]; }
        psum += __shfl_xor(psum, 32);
        l = l * alpha + psum; m = mnew;
        O0 *= alpha; O1 *= alpha;

        // P (C-layout) -> B-operand frags; PV: O^T += V^T (A, m=d) x P^T (B, n=q)
#pragma unroll
        for (int ks = 0; ks < 2; ++ks) {
            float lo[4], hi[4], plo[4], phi[4];
#pragma unroll
            for (int k = 0; k < 4; ++k) { lo[k] = P[ks * 8 + k]; hi[k] = P[ks * 8 + 4 + k]; }
#pragma unroll
            for (int k = 0; k < 4; ++k) { plo[k] = __shfl_xor(lo[k], 32); phi[k] = __shfl_xor(hi[k], 32); }
            bf16x8 pf;
#pragma unroll
            for (int k = 0; k < 4; ++k) {
                pf[k]     = (__bf16)(h5 ? phi[k] : lo[k]);
                pf[4 + k] = (__bf16)(h5 ? hi[k] : plo[k]);
            }
            int vc = ((ks * 2 + h5) ^ (l31 & 3)) * 8;
            bf16x8 v0 = *(const bf16x8*)(vt + l31 * 32 + vc);
            bf16x8 v1 = *(const bf16x8*)(vt + (l31 + 32) * 32 + vc);
            O0 = __builtin_amdgcn_mfma_f32_32x32x16_bf16(v0, pf, O0, 0, 0, 0);
            O1 = __builtin_amdgcn_mfma_f32_32x32x16_bf16(v1, pf, O1, 0, 0, 0);
        }
    }
    // epilogue: O^T col = q (lane), rows = d
    float linv = 1.f / l;
    float* orow = attn_out + (size_t)(b * SL + myq) * DD + h * 64;
#pragma unroll
    for (int r = 0; r < 16; ++r) {
        int dl = (r & 3) + 8 * (r >> 2) + 4 * h5;
        orow[dl] = O0[r] * linv;
        orow[dl + 32] = O1[r] * linv;
    }
}

// ======================= generic tiled GEMM: C[M,N] = A[M,K] @ W[N,K]^T =======================
// MODE 0: C = acc          MODE 1: C += acc
// MODE 2: x[(b*SL + sidx[m])*N + n] += acc * sprob[m]   (m -> b = m/KK)
// MODE 3: C = silu(C) * acc
template<int MODE>
__global__ __launch_bounds__(256) void gemm_bt(const float* __restrict__ A,
        const float* __restrict__ W, float* __restrict__ C, int M, int N, int K,
        const int* __restrict__ sidx, const float* __restrict__ sprob) {
    __shared__ float As[16][65];
    __shared__ float Ws[16][65];
    int tid = threadIdx.x;
    int tx = tid & 15, ty = tid >> 4;
    int m0 = blockIdx.y * 64, n0 = blockIdx.x * 64;
    int lrow = tid >> 2;
    int lk = (tid & 3) * 4;
    float acc[4][4] = {};
    for (int k0 = 0; k0 < K; k0 += 16) {
        float4 av = make_float4(0.f, 0.f, 0.f, 0.f), wv = make_float4(0.f, 0.f, 0.f, 0.f);
        if (m0 + lrow < M) av = *(const float4*)(A + (size_t)(m0 + lrow) * K + k0 + lk);
        if (n0 + lrow < N) wv = *(const float4*)(W + (size_t)(n0 + lrow) * K + k0 + lk);
        __syncthreads();
        As[lk + 0][lrow] = av.x; As[lk + 1][lrow] = av.y; As[lk + 2][lrow] = av.z; As[lk + 3][lrow] = av.w;
        Ws[lk + 0][lrow] = wv.x; Ws[lk + 1][lrow] = wv.y; Ws[lk + 2][lrow] = wv.z; Ws[lk + 3][lrow] = wv.w;
        __syncthreads();
#pragma unroll
        for (int k = 0; k < 16; ++k) {
            float a[4], w4[4];
#pragma unroll
            for (int i = 0; i < 4; ++i) a[i] = As[k][ty * 4 + i];
#pragma unroll
            for (int j = 0; j < 4; ++j) w4[j] = Ws[k][tx * 4 + j];
#pragma unroll
            for (int i = 0; i < 4; ++i)
#pragma unroll
                for (int j = 0; j < 4; ++j) acc[i][j] += a[i] * w4[j];
        }
    }
#pragma unroll
    for (int i = 0; i < 4; ++i) {
        int mm = m0 + ty * 4 + i;
        if (mm >= M) continue;
        float* crow;
        float scale = 1.f;
        if (MODE == 2) {
            int b = mm / KK;
            crow = C + ((size_t)(b * SL + sidx[mm])) * N;
            scale = sprob[mm];
        } else {
            crow = C + (size_t)mm * N;
        }
#pragma unroll
        for (int j = 0; j < 4; ++j) {
            int nn = n0 + tx * 4 + j;
            if (nn >= N) continue;
            if (MODE == 0) {
                crow[nn] = acc[i][j];
            } else if (MODE == 1) {
                crow[nn] += acc[i][j];
            } else if (MODE == 2) {
                crow[nn] += acc[i][j] * scale;
            } else {                                  // MODE 3: silu(gate) * up
                float c = crow[nn];
                crow[nn] = (c / (1.f + __expf(-c))) * acc[i][j];
            }
        }
    }
}

// ======================= launch =======================
extern "C" void kernel_launch(void* const* d_in, const int* in_sizes, int n_in,
                              void* d_out, int out_size, void* d_ws, size_t ws_size,
                              hipStream_t stream) {
    const int*   ids          = (const int*)d_in[0];
    const int*   iter         = (const int*)d_in[1];
    const float* emb          = (const float*)d_in[2];
    const float* iter_emb     = (const float*)d_in[3];
    const float* attn_norm_w  = (const float*)d_in[4];
    const float* Wqkv         = (const float*)d_in[5];
    const float* wo_w         = (const float*)d_in[6];
    const float* router_w     = (const float*)d_in[7];
    const float* mlp_norm_w   = (const float*)d_in[8];
    const float* gate_w       = (const float*)d_in[9];
    const float* up_w         = (const float*)d_in[10];
    const float* down_w       = (const float*)d_in[11];
    const float* final_norm_w = (const float*)d_in[12];
    float* out = (float*)d_out;

    const size_t XN   = (size_t)BB * SL * DD;        // 5,242,880
    const size_t QKVN = (size_t)BB * SL * 3 * DD;    // 15,728,640
    char* ws = (char*)d_ws;
    float* x        = (float*)(ws);
    float* h        = (float*)(ws + XN * 4);
    float* qkv      = (float*)(ws + 2 * XN * 4);      // fp32 qkv; reused as g-buffer later
    float* attn_out = (float*)(ws + 2 * XN * 4 + QKVN * 4);
    float* probs    = (float*)(ws + 3 * XN * 4 + QKVN * 4);
    int*   tkidx    = (int*)  (ws + 3 * XN * 4 + QKVN * 4 + 65536);
    float* tkprob   = (float*)(ws + 3 * XN * 4 + QKVN * 4 + 65536 + BB * KK * 4);
    float* g1       = qkv;                            // 45.3MB <= 62.9MB, qkv dead by then
    size_t bofs = 3 * XN * 4 + QKVN * 4 + 65536 + 2 * (size_t)BB * KK * 4;
    bofs = (bofs + 255) & ~(size_t)255;
    const size_t HN = (size_t)BB * NH * SL * 64;      // 5,242,880 elements (bf16)
    __bf16* Qb = (__bf16*)(ws + bofs);
    __bf16* Kb = (__bf16*)(ws + bofs + HN * 2);
    __bf16* Vb = (__bf16*)(ws + bofs + 2 * HN * 2);

    embed_kernel<<<20480, 256, 0, stream>>>(ids, iter, emb, iter_emb, x);

    for (int l = 0; l < NL; ++l) {
        rmsnorm_kernel<<<4096, 256, 0, stream>>>(x, attn_norm_w + l * DD, h, BB * SL);
        gemm_bt<0><<<dim3(15, 256), 256, 0, stream>>>(h, Wqkv + (size_t)l * 3 * DD * DD, qkv,
                                                      BB * SL, 3 * DD, DD, nullptr, nullptr);
        prep_kernel<<<dim3(SL / 64, NH, BB), 256, 0, stream>>>(qkv, Qb, Kb, Vb);
        attn_mfma<<<dim3(SL / 128, NH, BB), 256, 0, stream>>>(Qb, Kb, Vb, attn_out);
        gemm_bt<1><<<dim3(5, 256), 256, 0, stream>>>(attn_out, wo_w + (size_t)l * DD * DD, x,
                                                     BB * SL, DD, DD, nullptr, nullptr);
        router_kernel<<<4096, 256, 0, stream>>>(x, router_w + l * DD, probs, BB * SL);
        topk_kernel<<<BB, 1024, 0, stream>>>(probs, tkidx, tkprob);
        gather_rmsnorm_kernel<<<3276, 256, 0, stream>>>(x, tkidx, mlp_norm_w + l * DD, h, BB * KK);
        gemm_bt<0><<<dim3(14, 205), 256, 0, stream>>>(h, gate_w + (size_t)l * FF * DD, g1,
                                                      BB * KK, FF, DD, nullptr, nullptr);
        gemm_bt<3><<<dim3(14, 205), 256, 0, stream>>>(h, up_w + (size_t)l * FF * DD, g1,
                                                      BB * KK, FF, DD, nullptr, nullptr);
        gemm_bt<2><<<dim3(5, 205), 256, 0, stream>>>(g1, down_w + (size_t)l * DD * FF, x,
                                                     BB * KK, DD, FF, tkidx, tkprob);
    }
    rmsnorm_kernel<<<4096, 256, 0, stream>>>(x, final_norm_w, out, BB * SL);
}

// Round 3
// 2400.606 us; speedup vs baseline: 6.0716x; 2.3886x over previous
//
#include <hip/hip_runtime.h>
#include <hip/hip_bf16.h>
#include <math.h>

#define VSZ 1056
#define DD 320
#define NH 5
#define HD 64
#define FF 864
#define NL 6
#define NLOOPS 8
#define BB 8
#define SL 2048
#define KK 1638          // int(2048 * 0.8)
#define EPSF 1e-6f

typedef _Float16 f16x8 __attribute__((ext_vector_type(8)));
typedef _Float16 f16x4 __attribute__((ext_vector_type(4)));
typedef float floatx16 __attribute__((ext_vector_type(16)));

__device__ inline void gll16(const void* g, void* l) {
    __builtin_amdgcn_global_load_lds((const __attribute__((address_space(1))) void*)g,
                                     (__attribute__((address_space(3))) void*)l, 16, 0, 0);
}

// ======================= cast fp32 -> fp16 (x4) =======================
__global__ __launch_bounds__(256) void cast4_kernel(const float* __restrict__ s,
        _Float16* __restrict__ d, int n4) {
    int i = blockIdx.x * 256 + threadIdx.x;
    if (i >= n4) return;
    float4 v = ((const float4*)s)[i];
    f16x4 o = { (_Float16)v.x, (_Float16)v.y, (_Float16)v.z, (_Float16)v.w };
    *(f16x4*)(d + (size_t)i * 4) = o;
}

// ======================= embed =======================
__global__ __launch_bounds__(256) void embed_kernel(const int* __restrict__ ids,
        const int* __restrict__ iter, const float* __restrict__ emb,
        const float* __restrict__ iter_emb, float* __restrict__ x) {
    int i = blockIdx.x * 256 + threadIdx.x;          // over B*S*D
    int d = i % DD, bs = i / DD;
    float v = emb[(size_t)ids[bs] * DD + d];
    int it = iter[0];
    if (it < NLOOPS) v += iter_emb[it * DD + d];
    x[i] = v;
}

// ======================= rmsnorm (1 wave per row, D=320 -> 5/lane) =======================
template<typename OT>
__global__ __launch_bounds__(256) void rmsnorm_kernel(const float* __restrict__ x,
        const float* __restrict__ w, OT* __restrict__ out, int nrows) {
    int row = blockIdx.x * 4 + (threadIdx.x >> 6);
    int lane = threadIdx.x & 63;
    if (row >= nrows) return;
    const float* xr = x + (size_t)row * DD;
    float v[5]; float ss = 0.f;
#pragma unroll
    for (int i = 0; i < 5; ++i) { v[i] = xr[lane + i * 64]; ss += v[i] * v[i]; }
#pragma unroll
    for (int o = 32; o > 0; o >>= 1) ss += __shfl_xor(ss, o);
    float r = rsqrtf(ss * (1.f / DD) + EPSF);
    OT* orow = out + (size_t)row * DD;
#pragma unroll
    for (int i = 0; i < 5; ++i) orow[lane + i * 64] = (OT)(w[lane + i * 64] * v[i] * r);
}

// gather selected tokens + rmsnorm -> fp16
__global__ __launch_bounds__(256) void gather_rmsnorm_kernel(const float* __restrict__ x,
        const int* __restrict__ tkidx, const float* __restrict__ w,
        _Float16* __restrict__ out, int nrows) {
    int row = blockIdx.x * 4 + (threadIdx.x >> 6);
    int lane = threadIdx.x & 63;
    if (row >= nrows) return;
    int b = row / KK;
    int t = tkidx[row];
    const float* xr = x + ((size_t)b * SL + t) * DD;
    float v[5]; float ss = 0.f;
#pragma unroll
    for (int i = 0; i < 5; ++i) { v[i] = xr[lane + i * 64]; ss += v[i] * v[i]; }
#pragma unroll
    for (int o = 32; o > 0; o >>= 1) ss += __shfl_xor(ss, o);
    float r = rsqrtf(ss * (1.f / DD) + EPSF);
    _Float16* orow = out + (size_t)row * DD;
#pragma unroll
    for (int i = 0; i < 5; ++i) orow[lane + i * 64] = (_Float16)(w[lane + i * 64] * v[i] * r);
}

// ======================= router: sigmoid(x . rw) =======================
__global__ __launch_bounds__(256) void router_kernel(const float* __restrict__ x,
        const float* __restrict__ rw, float* __restrict__ probs, int nrows) {
    int row = blockIdx.x * 4 + (threadIdx.x >> 6);
    int lane = threadIdx.x & 63;
    if (row >= nrows) return;
    const float* xr = x + (size_t)row * DD;
    float ss = 0.f;
#pragma unroll
    for (int i = 0; i < 5; ++i) ss += xr[lane + i * 64] * rw[lane + i * 64];
#pragma unroll
    for (int o = 32; o > 0; o >>= 1) ss += __shfl_xor(ss, o);
    if (lane == 0) probs[row] = 1.f / (1.f + __expf(-ss));
}

// ======================= top-k: exact bitonic sort (desc value, asc index) =======================
__global__ __launch_bounds__(1024) void topk_kernel(const float* __restrict__ probs,
        int* __restrict__ tkidx, float* __restrict__ tkprob) {
    __shared__ unsigned long long keys[SL];
    int b = blockIdx.x, tid = threadIdx.x;
    for (int i = tid; i < SL; i += 1024) {
        unsigned int fb = __float_as_uint(probs[b * SL + i]);  // sigmoid > 0 -> bits monotonic
        keys[i] = ((unsigned long long)fb << 32) | (unsigned int)(SL - 1 - i);
    }
    __syncthreads();
    for (int k = 2; k <= SL; k <<= 1) {
        for (int j = k >> 1; j > 0; j >>= 1) {
            for (int i = tid; i < SL; i += 1024) {
                int ixj = i ^ j;
                if (ixj > i) {
                    unsigned long long a = keys[i], c = keys[ixj];
                    bool up = ((i & k) == 0);   // descending overall
                    if (up ? (a < c) : (a > c)) { keys[i] = c; keys[ixj] = a; }
                }
            }
            __syncthreads();
        }
    }
    for (int i = tid; i < KK; i += 1024) {
        unsigned long long key = keys[i];
        tkidx[b * KK + i] = (SL - 1) - (int)(key & 0xffffffffu);
        tkprob[b * KK + i] = __uint_as_float((unsigned int)(key >> 32));
    }
}

// ======================= prep: RoPE, Q scaled by 1/8, V transposed (all fp16) =======================
// qkv fp16 [b][s][3][NH][64] -> Qh [bh][s][64] (x0.125, roped), Kh [bh][s][64] (roped),
//                              Vh [bh][64][s]
__global__ __launch_bounds__(256) void prep_kernel(const _Float16* __restrict__ qkv,
        _Float16* __restrict__ Qh, _Float16* __restrict__ Kh, _Float16* __restrict__ Vh) {
    __shared__ _Float16 vt[64][72];
    int tid = threadIdx.x;
    int s0 = blockIdx.x * 64, h = blockIdx.y, b = blockIdx.z;
    int bh = b * NH + h;
#pragma unroll
    for (int p = 0; p < 16; ++p) {
        int idx = p * 256 + tid;                 // 64 s x 64 d
        int sl = idx >> 6, d = idx & 63;
        int s = s0 + sl;
        size_t rbase = ((size_t)(b * SL + s) * 3) * (NH * 64) + h * 64;
        float qv = (float)qkv[rbase + d], qp = (float)qkv[rbase + (d ^ 32)];
        float kv = (float)qkv[rbase + NH * 64 + d], kp = (float)qkv[rbase + NH * 64 + (d ^ 32)];
        float vv = (float)qkv[rbase + 2 * NH * 64 + d];
        float freq = exp2f(-(float)(d & 31) * 0.4152410118609203f);   // 10000^(-j/32)
        float ang = (float)s * freq;
        float c = cosf(ang), sn = sinf(ang);
        float qr = (d < 32) ? qv * c - qp * sn : qv * c + qp * sn;
        float kr = (d < 32) ? kv * c - kp * sn : kv * c + kp * sn;
        Qh[((size_t)bh * SL + s) * 64 + d] = (_Float16)(qr * 0.125f);
        Kh[((size_t)bh * SL + s) * 64 + d] = (_Float16)kr;
        vt[sl][d] = (_Float16)vv;
    }
    __syncthreads();
#pragma unroll
    for (int p = 0; p < 16; ++p) {
        int idx = p * 256 + tid;                 // 64 d x 64 s
        int d = idx >> 6, sl = idx & 63;
        Vh[((size_t)bh * 64 + d) * SL + s0 + sl] = vt[sl][d];
    }
}

// ======================= attention: MFMA 32x32x16 f16 flash, S^T/O^T orientation =======================
__global__ __launch_bounds__(256) void attn_mfma(const _Float16* __restrict__ Qh,
        const _Float16* __restrict__ Kh, const _Float16* __restrict__ Vh,
        _Float16* __restrict__ attn_out) {
    __shared__ __attribute__((aligned(16))) _Float16 kt[2048];   // 32 keys x 8 chunks x 8 (XOR swizzle)
    __shared__ __attribute__((aligned(16))) _Float16 vt[2048];   // 64 d    x 4 chunks x 8 (XOR swizzle)
    int tid = threadIdx.x;
    int wave = tid >> 6, lane = tid & 63;
    int l31 = lane & 31, h5 = lane >> 5;
    int bx = (int)(gridDim.x - 1) - (int)blockIdx.x;   // longest blocks first
    int h = blockIdx.y, b = blockIdx.z;
    int bh = b * NH + h;
    int qw = bx * 128 + wave * 32;
    int myq = qw + l31;

    f16x8 qf[4];
    const _Float16* qrow = Qh + ((size_t)bh * SL + myq) * 64;
#pragma unroll
    for (int kd = 0; kd < 4; ++kd)
        qf[kd] = *(const f16x8*)(qrow + kd * 16 + h5 * 8);

    floatx16 O0, O1;
#pragma unroll
    for (int r = 0; r < 16; ++r) { O0[r] = 0.f; O1[r] = 0.f; }
    float m = -INFINITY, l = 0.f;

    int ntiles = bx * 4 + 4;
    for (int t = 0; t < ntiles; ++t) {
        int t0 = t * 32;
        __syncthreads();
        {
            int key = tid >> 3, c = tid & 7;
            *(uint4*)(kt + key * 64 + ((c ^ (key & 7)) * 8)) =
                *(const uint4*)(Kh + ((size_t)bh * SL + t0 + key) * 64 + c * 8);
            int d = tid >> 2, c2 = tid & 3;
            *(uint4*)(vt + d * 32 + ((c2 ^ (d & 3)) * 8)) =
                *(const uint4*)(Vh + ((size_t)bh * 64 + d) * SL + t0 + c2 * 8);
        }
        __syncthreads();
        if (t0 > qw + 31) continue;              // wave-uniform; syncs stay aligned

        // S^T = K (A, m=key) x Q (B, n=q): C col = q = l31, row = key
        floatx16 S;
#pragma unroll
        for (int r = 0; r < 16; ++r) S[r] = 0.f;
#pragma unroll
        for (int kd = 0; kd < 4; ++kd) {
            f16x8 af = *(const f16x8*)(kt + l31 * 64 + (((kd * 2 + h5) ^ (l31 & 7)) * 8));
            S = __builtin_amdgcn_mfma_f32_32x32x16_f16(af, qf[kd], S, 0, 0, 0);
        }
        if (t0 + 31 > qw) {                      // diagonal tile: causal mask
#pragma unroll
            for (int r = 0; r < 16; ++r) {
                int key = t0 + (r & 3) + 8 * (r >> 2) + 4 * h5;
                S[r] = (key > myq) ? -INFINITY : S[r];
            }
        }
        // online softmax over keys (rows): in-lane regs + cross-half shfl
        float tmax = S[0];
#pragma unroll
        for (int r = 1; r < 16; ++r) tmax = fmaxf(tmax, S[r]);
        tmax = fmaxf(tmax, __shfl_xor(tmax, 32));
        float mnew = fmaxf(m, tmax);
        float alpha = __expf(m - mnew);
        float P[16]; float psum = 0.f;
#pragma unroll
        for (int r = 0; r < 16; ++r) { P[r] = __expf(S[r] - mnew); psum += P[r]; }
        psum += __shfl_xor(psum, 32);
        l = l * alpha + psum; m = mnew;
        O0 *= alpha; O1 *= alpha;

        // P (C-layout) -> B-operand frags; PV: O^T += V^T (A, m=d) x P^T (B, n=q)
#pragma unroll
        for (int ks = 0; ks < 2; ++ks) {
            float lo[4], hi[4], plo[4], phi[4];
#pragma unroll
            for (int k = 0; k < 4; ++k) { lo[k] = P[ks * 8 + k]; hi[k] = P[ks * 8 + 4 + k]; }
#pragma unroll
            for (int k = 0; k < 4; ++k) { plo[k] = __shfl_xor(lo[k], 32); phi[k] = __shfl_xor(hi[k], 32); }
            f16x8 pf;
#pragma unroll
            for (int k = 0; k < 4; ++k) {
                pf[k]     = (_Float16)(h5 ? phi[k] : lo[k]);
                pf[4 + k] = (_Float16)(h5 ? hi[k] : plo[k]);
            }
            int vc = ((ks * 2 + h5) ^ (l31 & 3)) * 8;
            f16x8 v0 = *(const f16x8*)(vt + l31 * 32 + vc);
            f16x8 v1 = *(const f16x8*)(vt + (l31 + 32) * 32 + vc);
            O0 = __builtin_amdgcn_mfma_f32_32x32x16_f16(v0, pf, O0, 0, 0, 0);
            O1 = __builtin_amdgcn_mfma_f32_32x32x16_f16(v1, pf, O1, 0, 0, 0);
        }
    }
    // epilogue: O^T col = q (lane), rows = d
    float linv = 1.f / l;
    _Float16* orow = attn_out + (size_t)(b * SL + myq) * DD + h * 64;
#pragma unroll
    for (int r = 0; r < 16; ++r) {
        int dl = (r & 3) + 8 * (r >> 2) + 4 * h5;
        orow[dl] = (_Float16)(O0[r] * linv);
        orow[dl + 32] = (_Float16)(O1[r] * linv);
    }
}

// ======================= MFMA GEMM: C[M,N] = A[M,K] @ W[N,K]^T (fp16 in, fp32 acc) ======
// 128x128 block tile, BK=32, 4 waves x (2x2 of 32x32x16), global_load_lds staging.
// MODE 0: Ch = acc (fp16)        MODE 1: X += acc (fp32)
// MODE 2: X[(b*SL+sidx[m])*N+n] += acc*sprob[m]
// MODE 3: Ch = silu(Ch) * acc (fp16)
template<int MODE>
__global__ __launch_bounds__(256) void gemm_mfma(const _Float16* __restrict__ A,
        const _Float16* __restrict__ W, _Float16* __restrict__ Ch, float* __restrict__ X,
        int M, int N, int K, const int* __restrict__ sidx, const float* __restrict__ sprob) {
    __shared__ __attribute__((aligned(16))) _Float16 As[4096];   // [kc][128 rows][8]
    __shared__ __attribute__((aligned(16))) _Float16 Ws[4096];
    int tid = threadIdx.x;
    int lane = tid & 63;
    int wave = tid >> 6;
    int l31 = lane & 31, h5 = lane >> 5;
    int m0 = blockIdx.y * 128, n0 = blockIdx.x * 128;
    int wm = (wave & 1) * 64, wn = (wave >> 1) * 64;

    // staging: chunk c = i*256 + tid -> row = c & 127, kc = c >> 7; LDS offset = c*8 halfs
    int srow = tid & 127;
    int skc = tid >> 7;                       // 0 or 1
    int arow = m0 + srow; if (arow >= M) arow = M - 1;
    int wrow = n0 + srow; if (wrow >= N) wrow = N - 1;
    const _Float16* Ag = A + (size_t)arow * K + skc * 8;
    const _Float16* Wg = W + (size_t)wrow * K + skc * 8;
    _Float16* AsD = As + (size_t)(tid & ~63) * 8;     // wave-uniform; +lane*16B implicit
    _Float16* WsD = Ws + (size_t)(tid & ~63) * 8;

    floatx16 acc[2][2];
#pragma unroll
    for (int i = 0; i < 2; ++i)
#pragma unroll
        for (int j = 0; j < 2; ++j)
#pragma unroll
            for (int r = 0; r < 16; ++r) acc[i][j][r] = 0.f;

    for (int k0 = 0; k0 < K; k0 += 32) {
        __syncthreads();
        gll16(Ag + k0, AsD);
        gll16(Ag + k0 + 16, AsD + 2048);
        gll16(Wg + k0, WsD);
        gll16(Wg + k0 + 16, WsD + 2048);
        __syncthreads();
#pragma unroll
        for (int ks = 0; ks < 2; ++ks) {
            int kc = ks * 2 + h5;
            f16x8 a0 = *(const f16x8*)(As + kc * 1024 + (wm + l31) * 8);
            f16x8 a1 = *(const f16x8*)(As + kc * 1024 + (wm + 32 + l31) * 8);
            f16x8 b0 = *(const f16x8*)(Ws + kc * 1024 + (wn + l31) * 8);
            f16x8 b1 = *(const f16x8*)(Ws + kc * 1024 + (wn + 32 + l31) * 8);
            acc[0][0] = __builtin_amdgcn_mfma_f32_32x32x16_f16(a0, b0, acc[0][0], 0, 0, 0);
            acc[0][1] = __builtin_amdgcn_mfma_f32_32x32x16_f16(a0, b1, acc[0][1], 0, 0, 0);
            acc[1][0] = __builtin_amdgcn_mfma_f32_32x32x16_f16(a1, b0, acc[1][0], 0, 0, 0);
            acc[1][1] = __builtin_amdgcn_mfma_f32_32x32x16_f16(a1, b1, acc[1][1], 0, 0, 0);
        }
    }

#pragma unroll
    for (int ti = 0; ti < 2; ++ti) {
#pragma unroll
        for (int r = 0; r < 16; ++r) {
            int mm = m0 + wm + ti * 32 + (r & 3) + 8 * (r >> 2) + 4 * h5;
            if (mm >= M) continue;
            float scale = 1.f;
            float* xrow = nullptr;
            _Float16* crow = nullptr;
            if (MODE == 2) {
                int b = mm / KK;
                scale = sprob[mm];
                xrow = X + ((size_t)(b * SL + sidx[mm])) * N;
            } else if (MODE == 1) {
                xrow = X + (size_t)mm * N;
            } else {
                crow = Ch + (size_t)mm * N;
            }
#pragma unroll
            for (int tj = 0; tj < 2; ++tj) {
                int nn = n0 + wn + tj * 32 + l31;
                if (nn >= N) continue;
                float v = acc[ti][tj][r];
                if (MODE == 0) {
                    crow[nn] = (_Float16)v;
                } else if (MODE == 1) {
                    xrow[nn] += v;
                } else if (MODE == 2) {
                    xrow[nn] += v * scale;
                } else {                                  // MODE 3: silu(gate) * up
                    float c = (float)crow[nn];
                    crow[nn] = (_Float16)((c / (1.f + __expf(-c))) * v);
                }
            }
        }
    }
}

// ======================= launch =======================
extern "C" void kernel_launch(void* const* d_in, const int* in_sizes, int n_in,
                              void* d_out, int out_size, void* d_ws, size_t ws_size,
                              hipStream_t stream) {
    const int*   ids          = (const int*)d_in[0];
    const int*   iter         = (const int*)d_in[1];
    const float* emb          = (const float*)d_in[2];
    const float* iter_emb     = (const float*)d_in[3];
    const float* attn_norm_w  = (const float*)d_in[4];
    const float* Wqkv         = (const float*)d_in[5];
    const float* wo_w         = (const float*)d_in[6];
    const float* router_w     = (const float*)d_in[7];
    const float* mlp_norm_w   = (const float*)d_in[8];
    const float* gate_w       = (const float*)d_in[9];
    const float* up_w         = (const float*)d_in[10];
    const float* down_w       = (const float*)d_in[11];
    const float* final_norm_w = (const float*)d_in[12];
    float* out = (float*)d_out;

    const size_t XN   = (size_t)BB * SL * DD;        // 5,242,880
    const size_t QKVN = (size_t)BB * SL * 3 * DD;    // 15,728,640
    const size_t HN   = (size_t)BB * NH * SL * 64;   // 5,242,880
    char* ws = (char*)d_ws;
    size_t off = 0;
    float*    x        = (float*)(ws + off);    off += XN * 4;
    _Float16* h        = (_Float16*)(ws + off); off += XN * 2;
    _Float16* attn_out = (_Float16*)(ws + off); off += XN * 2;
    float*    probs    = (float*)(ws + off);    off += (size_t)BB * SL * 4;
    int*      tkidx    = (int*)(ws + off);      off += (size_t)BB * KK * 4;
    float*    tkprob   = (float*)(ws + off);    off += (size_t)BB * KK * 4;
    off = (off + 255) & ~(size_t)255;
    _Float16* qkvh     = (_Float16*)(ws + off); off += QKVN * 2;   // reused as g1
    _Float16* Qh       = (_Float16*)(ws + off); off += HN * 2;
    _Float16* Kh       = (_Float16*)(ws + off); off += HN * 2;
    _Float16* Vh       = (_Float16*)(ws + off); off += HN * 2;
    _Float16* WqkvH    = (_Float16*)(ws + off);
    _Float16* woH   = WqkvH + (size_t)NL * 3 * DD * DD;    // 1,843,200
    _Float16* gateH = woH   + (size_t)NL * DD * DD;        //   614,400
    _Float16* upH   = gateH + (size_t)NL * FF * DD;        // 1,658,880
    _Float16* downH = upH   + (size_t)NL * FF * DD;        // 1,658,880
    _Float16* g1 = qkvh;

    // weight casts (every call; harness re-poisons ws)
    cast4_kernel<<<(NL * 3 * DD * DD / 4 + 255) / 256, 256, 0, stream>>>(Wqkv, WqkvH, NL * 3 * DD * DD / 4);
    cast4_kernel<<<(NL * DD * DD / 4 + 255) / 256, 256, 0, stream>>>(wo_w, woH, NL * DD * DD / 4);
    cast4_kernel<<<(NL * FF * DD / 4 + 255) / 256, 256, 0, stream>>>(gate_w, gateH, NL * FF * DD / 4);
    cast4_kernel<<<(NL * FF * DD / 4 + 255) / 256, 256, 0, stream>>>(up_w, upH, NL * FF * DD / 4);
    cast4_kernel<<<(NL * DD * FF / 4 + 255) / 256, 256, 0, stream>>>(down_w, downH, NL * DD * FF / 4);

    embed_kernel<<<20480, 256, 0, stream>>>(ids, iter, emb, iter_emb, x);

    const int M1 = BB * SL;    // 16384
    const int M2 = BB * KK;    // 13104
    for (int l = 0; l < NL; ++l) {
        rmsnorm_kernel<_Float16><<<4096, 256, 0, stream>>>(x, attn_norm_w + l * DD, h, M1);
        gemm_mfma<0><<<dim3(8, 128), 256, 0, stream>>>(h, WqkvH + (size_t)l * 3 * DD * DD,
                                                       qkvh, nullptr, M1, 3 * DD, DD, nullptr, nullptr);
        prep_kernel<<<dim3(SL / 64, NH, BB), 256, 0, stream>>>(qkvh, Qh, Kh, Vh);
        attn_mfma<<<dim3(SL / 128, NH, BB), 256, 0, stream>>>(Qh, Kh, Vh, attn_out);
        gemm_mfma<1><<<dim3(3, 128), 256, 0, stream>>>(attn_out, woH + (size_t)l * DD * DD,
                                                       nullptr, x, M1, DD, DD, nullptr, nullptr);
        router_kernel<<<4096, 256, 0, stream>>>(x, router_w + l * DD, probs, M1);
        topk_kernel<<<BB, 1024, 0, stream>>>(probs, tkidx, tkprob);
        gather_rmsnorm_kernel<<<3276, 256, 0, stream>>>(x, tkidx, mlp_norm_w + l * DD, h, M2);
        gemm_mfma<0><<<dim3(7, 103), 256, 0, stream>>>(h, gateH + (size_t)l * FF * DD,
                                                       g1, nullptr, M2, FF, DD, nullptr, nullptr);
        gemm_mfma<3><<<dim3(7, 103), 256, 0, stream>>>(h, upH + (size_t)l * FF * DD,
                                                       g1, nullptr, M2, FF, DD, nullptr, nullptr);
        gemm_mfma<2><<<dim3(3, 103), 256, 0, stream>>>(g1, downH + (size_t)l * DD * FF,
                                                       nullptr, x, M2, DD, FF, tkidx, tkprob);
    }
    rmsnorm_kernel<float><<<4096, 256, 0, stream>>>(x, final_norm_w, out, M1);
}

// Round 4
// 2177.219 us; speedup vs baseline: 6.6945x; 1.1026x over previous
//
#include <hip/hip_runtime.h>
#include <hip/hip_bf16.h>
#include <math.h>

#define VSZ 1056
#define DD 320
#define NH 5
#define HD 64
#define FF 864
#define NL 6
#define NLOOPS 8
#define BB 8
#define SL 2048
#define KK 1638          // int(2048 * 0.8)
#define EPSF 1e-6f

typedef _Float16 f16x8 __attribute__((ext_vector_type(8)));
typedef _Float16 f16x4 __attribute__((ext_vector_type(4)));
typedef float floatx16 __attribute__((ext_vector_type(16)));

__device__ inline void gll16(const void* g, void* l) {
    __builtin_amdgcn_global_load_lds((const __attribute__((address_space(1))) void*)g,
                                     (__attribute__((address_space(3))) void*)l, 16, 0, 0);
}

// ======================= cast fp32 -> fp16 (x4) =======================
__global__ __launch_bounds__(256) void cast4_kernel(const float* __restrict__ s,
        _Float16* __restrict__ d, int n4) {
    int i = blockIdx.x * 256 + threadIdx.x;
    if (i >= n4) return;
    float4 v = ((const float4*)s)[i];
    f16x4 o = { (_Float16)v.x, (_Float16)v.y, (_Float16)v.z, (_Float16)v.w };
    *(f16x4*)(d + (size_t)i * 4) = o;
}

// ======================= embed =======================
__global__ __launch_bounds__(256) void embed_kernel(const int* __restrict__ ids,
        const int* __restrict__ iter, const float* __restrict__ emb,
        const float* __restrict__ iter_emb, float* __restrict__ x) {
    int i = blockIdx.x * 256 + threadIdx.x;          // over B*S*D
    int d = i % DD, bs = i / DD;
    float v = emb[(size_t)ids[bs] * DD + d];
    int it = iter[0];
    if (it < NLOOPS) v += iter_emb[it * DD + d];
    x[i] = v;
}

// ======================= rmsnorm (1 wave per row, D=320 -> 5/lane) =======================
template<typename OT>
__global__ __launch_bounds__(256) void rmsnorm_kernel(const float* __restrict__ x,
        const float* __restrict__ w, OT* __restrict__ out, int nrows) {
    int row = blockIdx.x * 4 + (threadIdx.x >> 6);
    int lane = threadIdx.x & 63;
    if (row >= nrows) return;
    const float* xr = x + (size_t)row * DD;
    float v[5]; float ss = 0.f;
#pragma unroll
    for (int i = 0; i < 5; ++i) { v[i] = xr[lane + i * 64]; ss += v[i] * v[i]; }
#pragma unroll
    for (int o = 32; o > 0; o >>= 1) ss += __shfl_xor(ss, o);
    float r = rsqrtf(ss * (1.f / DD) + EPSF);
    OT* orow = out + (size_t)row * DD;
#pragma unroll
    for (int i = 0; i < 5; ++i) orow[lane + i * 64] = (OT)(w[lane + i * 64] * v[i] * r);
}

// gather selected tokens + rmsnorm -> fp16
__global__ __launch_bounds__(256) void gather_rmsnorm_kernel(const float* __restrict__ x,
        const int* __restrict__ tkidx, const float* __restrict__ w,
        _Float16* __restrict__ out, int nrows) {
    int row = blockIdx.x * 4 + (threadIdx.x >> 6);
    int lane = threadIdx.x & 63;
    if (row >= nrows) return;
    int b = row / KK;
    int t = tkidx[row];
    const float* xr = x + ((size_t)b * SL + t) * DD;
    float v[5]; float ss = 0.f;
#pragma unroll
    for (int i = 0; i < 5; ++i) { v[i] = xr[lane + i * 64]; ss += v[i] * v[i]; }
#pragma unroll
    for (int o = 32; o > 0; o >>= 1) ss += __shfl_xor(ss, o);
    float r = rsqrtf(ss * (1.f / DD) + EPSF);
    _Float16* orow = out + (size_t)row * DD;
#pragma unroll
    for (int i = 0; i < 5; ++i) orow[lane + i * 64] = (_Float16)(w[lane + i * 64] * v[i] * r);
}

// ======================= router: sigmoid(x . rw) =======================
__global__ __launch_bounds__(256) void router_kernel(const float* __restrict__ x,
        const float* __restrict__ rw, float* __restrict__ probs, int nrows) {
    int row = blockIdx.x * 4 + (threadIdx.x >> 6);
    int lane = threadIdx.x & 63;
    if (row >= nrows) return;
    const float* xr = x + (size_t)row * DD;
    float ss = 0.f;
#pragma unroll
    for (int i = 0; i < 5; ++i) ss += xr[lane + i * 64] * rw[lane + i * 64];
#pragma unroll
    for (int o = 32; o > 0; o >>= 1) ss += __shfl_xor(ss, o);
    if (lane == 0) probs[row] = 1.f / (1.f + __expf(-ss));
}

// ======================= top-k: radix select on packed (probbits<<32 | 2047-i) ===========
// Selection order is free: gather and scatter both go through tkidx[row], so only the
// selected SET matters. Tie semantics (value desc, index asc) exact via packed key.
__global__ __launch_bounds__(1024) void topk_kernel(const float* __restrict__ probs,
        int* __restrict__ tkidx, float* __restrict__ tkprob) {
    __shared__ int hist[256];
    __shared__ int scn[256];
    __shared__ int outc;
    __shared__ int s_digit, s_rem;
    int b = blockIdx.x, tid = threadIdx.x;
    unsigned long long k0, k1;
    {
        unsigned int f0 = __float_as_uint(probs[b * SL + tid]);
        unsigned int f1 = __float_as_uint(probs[b * SL + tid + 1024]);
        k0 = ((unsigned long long)f0 << 32) | (unsigned int)(2047 - tid);
        k1 = ((unsigned long long)f1 << 32) | (unsigned int)(2047 - (tid + 1024));
    }
    if (tid == 0) outc = 0;
    unsigned long long prefix = 0, pmask = 0;
    int target = KK;
    for (int shift = 56; shift >= 0; shift -= 8) {
        if (tid < 256) hist[tid] = 0;
        __syncthreads();
        bool a0 = (k0 & pmask) == prefix;
        bool a1 = (k1 & pmask) == prefix;
        int d0 = (int)((k0 >> shift) & 255);
        int d1 = (int)((k1 >> shift) & 255);
        if (a0) atomicAdd(&hist[d0], 1);
        if (a1) atomicAdd(&hist[d1], 1);
        __syncthreads();
        if (tid < 256) scn[tid] = hist[tid];
        __syncthreads();
#pragma unroll
        for (int st = 1; st < 256; st <<= 1) {       // suffix inclusive scan
            int v = 0;
            if (tid < 256 && tid + st < 256) v = scn[tid + st];
            __syncthreads();
            if (tid < 256) scn[tid] += v;
            __syncthreads();
        }
        if (tid < 256 && hist[tid] > 0) {
            int S = scn[tid];                 // count digit >= tid
            int Sgt = S - hist[tid];          // count digit >  tid
            if (Sgt < target && target <= S) { s_digit = tid; s_rem = target - Sgt; }
        }
        __syncthreads();
        int dsel = s_digit, rem = s_rem;
        bool full = (rem == hist[dsel]);
        if (a0 && (d0 > dsel || (full && d0 == dsel))) {
            int s = atomicAdd(&outc, 1);
            tkidx[b * KK + s] = 2047 - (int)(k0 & 0xffffffffu);
            tkprob[b * KK + s] = __uint_as_float((unsigned int)(k0 >> 32));
        }
        if (a1 && (d1 > dsel || (full && d1 == dsel))) {
            int s = atomicAdd(&outc, 1);
            tkidx[b * KK + s] = 2047 - (int)(k1 & 0xffffffffu);
            tkprob[b * KK + s] = __uint_as_float((unsigned int)(k1 >> 32));
        }
        if (full) break;
        target = rem;
        prefix |= ((unsigned long long)dsel) << shift;
        pmask  |= ((unsigned long long)255) << shift;
        __syncthreads();                      // protect hist/scn before next-pass zeroing
    }
}

// ======================= prep: RoPE, Q scaled by 1/8, V transposed (all fp16) =======================
__global__ __launch_bounds__(256) void prep_kernel(const _Float16* __restrict__ qkv,
        _Float16* __restrict__ Qh, _Float16* __restrict__ Kh, _Float16* __restrict__ Vh) {
    __shared__ _Float16 vt[64][72];
    int tid = threadIdx.x;
    int s0 = blockIdx.x * 64, h = blockIdx.y, b = blockIdx.z;
    int bh = b * NH + h;
#pragma unroll
    for (int p = 0; p < 16; ++p) {
        int idx = p * 256 + tid;                 // 64 s x 64 d
        int sl = idx >> 6, d = idx & 63;
        int s = s0 + sl;
        size_t rbase = ((size_t)(b * SL + s) * 3) * (NH * 64) + h * 64;
        float qv = (float)qkv[rbase + d], qp = (float)qkv[rbase + (d ^ 32)];
        float kv = (float)qkv[rbase + NH * 64 + d], kp = (float)qkv[rbase + NH * 64 + (d ^ 32)];
        float vv = (float)qkv[rbase + 2 * NH * 64 + d];
        float freq = exp2f(-(float)(d & 31) * 0.4152410118609203f);   // 10000^(-j/32)
        float ang = (float)s * freq;
        float c = cosf(ang), sn = sinf(ang);
        float qr = (d < 32) ? qv * c - qp * sn : qv * c + qp * sn;
        float kr = (d < 32) ? kv * c - kp * sn : kv * c + kp * sn;
        Qh[((size_t)bh * SL + s) * 64 + d] = (_Float16)(qr * 0.125f);
        Kh[((size_t)bh * SL + s) * 64 + d] = (_Float16)kr;
        vt[sl][d] = (_Float16)vv;
    }
    __syncthreads();
#pragma unroll
    for (int p = 0; p < 16; ++p) {
        int idx = p * 256 + tid;                 // 64 d x 64 s
        int d = idx >> 6, sl = idx & 63;
        Vh[((size_t)bh * 64 + d) * SL + s0 + sl] = vt[sl][d];
    }
}

// ======= attention: MFMA 32x32x16 f16 flash, 64-key dbuf tiles, 1 barrier/tile =========
__global__ __launch_bounds__(256) void attn_mfma(const _Float16* __restrict__ Qh,
        const _Float16* __restrict__ Kh, const _Float16* __restrict__ Vh,
        _Float16* __restrict__ attn_out) {
    __shared__ __attribute__((aligned(16))) _Float16 kt[2][4096];  // 64 keys x 8 chunks x 8, XOR swizzle
    __shared__ __attribute__((aligned(16))) _Float16 vt[2][4096];  // 64 d    x 8 chunks x 8, XOR swizzle
    int tid = threadIdx.x;
    int wave = tid >> 6, lane = tid & 63;
    int l31 = lane & 31, h5 = lane >> 5;
    int bx = (int)(gridDim.x - 1) - (int)blockIdx.x;   // longest blocks first
    int h = blockIdx.y, b = blockIdx.z;
    int bh = b * NH + h;
    int qw = bx * 128 + wave * 32;
    int myq = qw + l31;

    f16x8 qf[4];
    const _Float16* qrow = Qh + ((size_t)bh * SL + myq) * 64;
#pragma unroll
    for (int kd = 0; kd < 4; ++kd)
        qf[kd] = *(const f16x8*)(qrow + kd * 16 + h5 * 8);

    // staging: thread -> row (0..63), two chunks (sc, sc+1)
    int srow = tid >> 2;
    int sc = (tid & 3) * 2;
    const _Float16* Kg = Kh + ((size_t)bh * SL + srow) * 64 + sc * 8;
    const _Float16* Vg = Vh + ((size_t)bh * 64 + srow) * SL + sc * 8;
    int ko0 = srow * 64 + ((sc ^ (srow & 7)) * 8);
    int ko1 = srow * 64 + (((sc + 1) ^ (srow & 7)) * 8);
    int nt = 2 * bx + 2;

    floatx16 O0, O1;
#pragma unroll
    for (int r = 0; r < 16; ++r) { O0[r] = 0.f; O1[r] = 0.f; }
    float m = -INFINITY, l = 0.f;

    uint4 ka0 = *(const uint4*)(Kg);
    uint4 ka1 = *(const uint4*)(Kg + 8);
    uint4 va0 = *(const uint4*)(Vg);
    uint4 va1 = *(const uint4*)(Vg + 8);

    for (int t = 0; t < nt; ++t) {
        int buf = t & 1;
        *(uint4*)(kt[buf] + ko0) = ka0;
        *(uint4*)(kt[buf] + ko1) = ka1;
        *(uint4*)(vt[buf] + ko0) = va0;
        *(uint4*)(vt[buf] + ko1) = va1;
        __syncthreads();
        if (t + 1 < nt) {                        // prefetch next tile (overlaps compute)
            int t0n = (t + 1) * 64;
            ka0 = *(const uint4*)(Kg + (size_t)t0n * 64);
            ka1 = *(const uint4*)(Kg + (size_t)t0n * 64 + 8);
            va0 = *(const uint4*)(Vg + t0n);
            va1 = *(const uint4*)(Vg + t0n + 8);
        }
        int t0 = t * 64;
        if (t0 <= qw + 31) {                     // wave-uniform compute guard
            const _Float16* ktb = kt[buf];
            const _Float16* vtb = vt[buf];
            // S^T = K (A, m=key) x Q (B, n=q); two 32-key subtiles
            floatx16 S0, S1;
#pragma unroll
            for (int r = 0; r < 16; ++r) { S0[r] = 0.f; S1[r] = 0.f; }
#pragma unroll
            for (int kd = 0; kd < 4; ++kd) {
                int cix = ((kd * 2 + h5) ^ (l31 & 7)) * 8;
                f16x8 a0 = *(const f16x8*)(ktb + l31 * 64 + cix);
                f16x8 a1 = *(const f16x8*)(ktb + (l31 + 32) * 64 + cix);
                S0 = __builtin_amdgcn_mfma_f32_32x32x16_f16(a0, qf[kd], S0, 0, 0, 0);
                S1 = __builtin_amdgcn_mfma_f32_32x32x16_f16(a1, qf[kd], S1, 0, 0, 0);
            }
            if (t0 + 63 > qw) {                  // causal mask on diagonal tiles
#pragma unroll
                for (int r = 0; r < 16; ++r) {
                    int key = t0 + (r & 3) + 8 * (r >> 2) + 4 * h5;
                    if (key > myq) S0[r] = -INFINITY;
                    if (key + 32 > myq) S1[r] = -INFINITY;
                }
            }
            float tmax = S0[0];
#pragma unroll
            for (int r = 1; r < 16; ++r) tmax = fmaxf(tmax, S0[r]);
#pragma unroll
            for (int r = 0; r < 16; ++r) tmax = fmaxf(tmax, S1[r]);
            tmax = fmaxf(tmax, __shfl_xor(tmax, 32));
            float mnew = fmaxf(m, tmax);
            float alpha = __expf(m - mnew);
            float P0[16], P1[16]; float psum = 0.f;
#pragma unroll
            for (int r = 0; r < 16; ++r) { P0[r] = __expf(S0[r] - mnew); psum += P0[r]; }
#pragma unroll
            for (int r = 0; r < 16; ++r) { P1[r] = __expf(S1[r] - mnew); psum += P1[r]; }
            psum += __shfl_xor(psum, 32);
            l = l * alpha + psum; m = mnew;
            O0 *= alpha; O1 *= alpha;
            // PV: O^T += V^T (A, m=d) x P^T (B, n=q); 4 k-chunks of 16 keys
#pragma unroll
            for (int sub = 0; sub < 2; ++sub) {
                const float* P = sub ? P1 : P0;
#pragma unroll
                for (int kk = 0; kk < 2; ++kk) {
                    float lo[4], hi[4], plo[4], phi[4];
#pragma unroll
                    for (int k = 0; k < 4; ++k) { lo[k] = P[kk * 8 + k]; hi[k] = P[kk * 8 + 4 + k]; }
#pragma unroll
                    for (int k = 0; k < 4; ++k) { plo[k] = __shfl_xor(lo[k], 32); phi[k] = __shfl_xor(hi[k], 32); }
                    f16x8 pf;
#pragma unroll
                    for (int k = 0; k < 4; ++k) {
                        pf[k]     = (_Float16)(h5 ? phi[k] : lo[k]);
                        pf[4 + k] = (_Float16)(h5 ? hi[k] : plo[k]);
                    }
                    int ksg = sub * 2 + kk;
                    int vcix = ((ksg * 2 + h5) ^ (l31 & 7)) * 8;
                    f16x8 v0 = *(const f16x8*)(vtb + l31 * 64 + vcix);
                    f16x8 v1 = *(const f16x8*)(vtb + (l31 + 32) * 64 + vcix);
                    O0 = __builtin_amdgcn_mfma_f32_32x32x16_f16(v0, pf, O0, 0, 0, 0);
                    O1 = __builtin_amdgcn_mfma_f32_32x32x16_f16(v1, pf, O1, 0, 0, 0);
                }
            }
        }
    }
    float linv = 1.f / l;
    _Float16* orow = attn_out + (size_t)(b * SL + myq) * DD + h * 64;
#pragma unroll
    for (int r = 0; r < 16; ++r) {
        int dl = (r & 3) + 8 * (r >> 2) + 4 * h5;
        orow[dl] = (_Float16)(O0[r] * linv);
        orow[dl + 32] = (_Float16)(O1[r] * linv);
    }
}

// ======================= MFMA GEMM: C[M,N] = A[M,K] @ W[N,K]^T (fp16 in, fp32 acc) ======
// MODE 0: Ch = acc (fp16)   MODE 1: X += acc (fp32)
// MODE 2: X[(b*SL+sidx[m])*N+n] += acc*sprob[m]
template<int MODE>
__global__ __launch_bounds__(256) void gemm_mfma(const _Float16* __restrict__ A,
        const _Float16* __restrict__ W, _Float16* __restrict__ Ch, float* __restrict__ X,
        int M, int N, int K, const int* __restrict__ sidx, const float* __restrict__ sprob) {
    __shared__ __attribute__((aligned(16))) _Float16 As[4096];   // [kc][128 rows][8]
    __shared__ __attribute__((aligned(16))) _Float16 Ws[4096];
    int tid = threadIdx.x;
    int lane = tid & 63;
    int wave = tid >> 6;
    int l31 = lane & 31, h5 = lane >> 5;
    int m0 = blockIdx.y * 128, n0 = blockIdx.x * 128;
    int wm = (wave & 1) * 64, wn = (wave >> 1) * 64;

    int srow = tid & 127;
    int skc = tid >> 7;
    int arow = m0 + srow; if (arow >= M) arow = M - 1;
    int wrow = n0 + srow; if (wrow >= N) wrow = N - 1;
    const _Float16* Ag = A + (size_t)arow * K + skc * 8;
    const _Float16* Wg = W + (size_t)wrow * K + skc * 8;
    _Float16* AsD = As + (size_t)(tid & ~63) * 8;
    _Float16* WsD = Ws + (size_t)(tid & ~63) * 8;

    floatx16 acc[2][2];
#pragma unroll
    for (int i = 0; i < 2; ++i)
#pragma unroll
        for (int j = 0; j < 2; ++j)
#pragma unroll
            for (int r = 0; r < 16; ++r) acc[i][j][r] = 0.f;

    for (int k0 = 0; k0 < K; k0 += 32) {
        __syncthreads();
        gll16(Ag + k0, AsD);
        gll16(Ag + k0 + 16, AsD + 2048);
        gll16(Wg + k0, WsD);
        gll16(Wg + k0 + 16, WsD + 2048);
        __syncthreads();
#pragma unroll
        for (int ks = 0; ks < 2; ++ks) {
            int kc = ks * 2 + h5;
            f16x8 a0 = *(const f16x8*)(As + kc * 1024 + (wm + l31) * 8);
            f16x8 a1 = *(const f16x8*)(As + kc * 1024 + (wm + 32 + l31) * 8);
            f16x8 b0 = *(const f16x8*)(Ws + kc * 1024 + (wn + l31) * 8);
            f16x8 b1 = *(const f16x8*)(Ws + kc * 1024 + (wn + 32 + l31) * 8);
            acc[0][0] = __builtin_amdgcn_mfma_f32_32x32x16_f16(a0, b0, acc[0][0], 0, 0, 0);
            acc[0][1] = __builtin_amdgcn_mfma_f32_32x32x16_f16(a0, b1, acc[0][1], 0, 0, 0);
            acc[1][0] = __builtin_amdgcn_mfma_f32_32x32x16_f16(a1, b0, acc[1][0], 0, 0, 0);
            acc[1][1] = __builtin_amdgcn_mfma_f32_32x32x16_f16(a1, b1, acc[1][1], 0, 0, 0);
        }
    }

#pragma unroll
    for (int ti = 0; ti < 2; ++ti) {
#pragma unroll
        for (int r = 0; r < 16; ++r) {
            int mm = m0 + wm + ti * 32 + (r & 3) + 8 * (r >> 2) + 4 * h5;
            if (mm >= M) continue;
            float scale = 1.f;
            float* xrow = nullptr;
            _Float16* crow = nullptr;
            if (MODE == 2) {
                int b = mm / KK;
                scale = sprob[mm];
                xrow = X + ((size_t)(b * SL + sidx[mm])) * N;
            } else if (MODE == 1) {
                xrow = X + (size_t)mm * N;
            } else {
                crow = Ch + (size_t)mm * N;
            }
#pragma unroll
            for (int tj = 0; tj < 2; ++tj) {
                int nn = n0 + wn + tj * 32 + l31;
                if (nn >= N) continue;
                float v = acc[ti][tj][r];
                if (MODE == 0) crow[nn] = (_Float16)v;
                else if (MODE == 1) xrow[nn] += v;
                else xrow[nn] += v * scale;
            }
        }
    }
}

// ============ fused gate+up GEMM: g1 = silu(A@Wg^T) * (A@Wu^T), fp16 out ============
__global__ __launch_bounds__(256) void gemm_gateup(const _Float16* __restrict__ A,
        const _Float16* __restrict__ Wg, const _Float16* __restrict__ Wu,
        _Float16* __restrict__ Ch, int M, int N, int K) {
    __shared__ __attribute__((aligned(16))) _Float16 As[4096];
    __shared__ __attribute__((aligned(16))) _Float16 Wgs[4096];
    __shared__ __attribute__((aligned(16))) _Float16 Wus[4096];
    int tid = threadIdx.x;
    int lane = tid & 63;
    int wave = tid >> 6;
    int l31 = lane & 31, h5 = lane >> 5;
    int m0 = blockIdx.y * 128, n0 = blockIdx.x * 128;
    int wm = (wave & 1) * 64, wn = (wave >> 1) * 64;

    int srow = tid & 127;
    int skc = tid >> 7;
    int arow = m0 + srow; if (arow >= M) arow = M - 1;
    int wrow = n0 + srow; if (wrow >= N) wrow = N - 1;
    const _Float16* Ag  = A  + (size_t)arow * K + skc * 8;
    const _Float16* Wgg = Wg + (size_t)wrow * K + skc * 8;
    const _Float16* Wug = Wu + (size_t)wrow * K + skc * 8;
    _Float16* AsD  = As  + (size_t)(tid & ~63) * 8;
    _Float16* WgsD = Wgs + (size_t)(tid & ~63) * 8;
    _Float16* WusD = Wus + (size_t)(tid & ~63) * 8;

    floatx16 ag[2][2], au[2][2];
#pragma unroll
    for (int i = 0; i < 2; ++i)
#pragma unroll
        for (int j = 0; j < 2; ++j)
#pragma unroll
            for (int r = 0; r < 16; ++r) { ag[i][j][r] = 0.f; au[i][j][r] = 0.f; }

    for (int k0 = 0; k0 < K; k0 += 32) {
        __syncthreads();
        gll16(Ag + k0, AsD);
        gll16(Ag + k0 + 16, AsD + 2048);
        gll16(Wgg + k0, WgsD);
        gll16(Wgg + k0 + 16, WgsD + 2048);
        gll16(Wug + k0, WusD);
        gll16(Wug + k0 + 16, WusD + 2048);
        __syncthreads();
#pragma unroll
        for (int ks = 0; ks < 2; ++ks) {
            int kc = ks * 2 + h5;
            f16x8 a0 = *(const f16x8*)(As + kc * 1024 + (wm + l31) * 8);
            f16x8 a1 = *(const f16x8*)(As + kc * 1024 + (wm + 32 + l31) * 8);
            f16x8 g0 = *(const f16x8*)(Wgs + kc * 1024 + (wn + l31) * 8);
            f16x8 g1f = *(const f16x8*)(Wgs + kc * 1024 + (wn + 32 + l31) * 8);
            f16x8 u0 = *(const f16x8*)(Wus + kc * 1024 + (wn + l31) * 8);
            f16x8 u1 = *(const f16x8*)(Wus + kc * 1024 + (wn + 32 + l31) * 8);
            ag[0][0] = __builtin_amdgcn_mfma_f32_32x32x16_f16(a0, g0, ag[0][0], 0, 0, 0);
            ag[0][1] = __builtin_amdgcn_mfma_f32_32x32x16_f16(a0, g1f, ag[0][1], 0, 0, 0);
            ag[1][0] = __builtin_amdgcn_mfma_f32_32x32x16_f16(a1, g0, ag[1][0], 0, 0, 0);
            ag[1][1] = __builtin_amdgcn_mfma_f32_32x32x16_f16(a1, g1f, ag[1][1], 0, 0, 0);
            au[0][0] = __builtin_amdgcn_mfma_f32_32x32x16_f16(a0, u0, au[0][0], 0, 0, 0);
            au[0][1] = __builtin_amdgcn_mfma_f32_32x32x16_f16(a0, u1, au[0][1], 0, 0, 0);
            au[1][0] = __builtin_amdgcn_mfma_f32_32x32x16_f16(a1, u0, au[1][0], 0, 0, 0);
            au[1][1] = __builtin_amdgcn_mfma_f32_32x32x16_f16(a1, u1, au[1][1], 0, 0, 0);
        }
    }

#pragma unroll
    for (int ti = 0; ti < 2; ++ti) {
#pragma unroll
        for (int r = 0; r < 16; ++r) {
            int mm = m0 + wm + ti * 32 + (r & 3) + 8 * (r >> 2) + 4 * h5;
            if (mm >= M) continue;
            _Float16* crow = Ch + (size_t)mm * N;
#pragma unroll
            for (int tj = 0; tj < 2; ++tj) {
                int nn = n0 + wn + tj * 32 + l31;
                if (nn >= N) continue;
                float gv = ag[ti][tj][r], uv = au[ti][tj][r];
                crow[nn] = (_Float16)((gv / (1.f + __expf(-gv))) * uv);
            }
        }
    }
}

// ======================= launch =======================
extern "C" void kernel_launch(void* const* d_in, const int* in_sizes, int n_in,
                              void* d_out, int out_size, void* d_ws, size_t ws_size,
                              hipStream_t stream) {
    const int*   ids          = (const int*)d_in[0];
    const int*   iter         = (const int*)d_in[1];
    const float* emb          = (const float*)d_in[2];
    const float* iter_emb     = (const float*)d_in[3];
    const float* attn_norm_w  = (const float*)d_in[4];
    const float* Wqkv         = (const float*)d_in[5];
    const float* wo_w         = (const float*)d_in[6];
    const float* router_w     = (const float*)d_in[7];
    const float* mlp_norm_w   = (const float*)d_in[8];
    const float* gate_w       = (const float*)d_in[9];
    const float* up_w         = (const float*)d_in[10];
    const float* down_w       = (const float*)d_in[11];
    const float* final_norm_w = (const float*)d_in[12];
    float* out = (float*)d_out;

    const size_t XN   = (size_t)BB * SL * DD;        // 5,242,880
    const size_t QKVN = (size_t)BB * SL * 3 * DD;    // 15,728,640
    const size_t HN   = (size_t)BB * NH * SL * 64;   // 5,242,880
    char* ws = (char*)d_ws;
    size_t off = 0;
    float*    x        = (float*)(ws + off);    off += XN * 4;
    _Float16* h        = (_Float16*)(ws + off); off += XN * 2;
    _Float16* attn_out = (_Float16*)(ws + off); off += XN * 2;
    float*    probs    = (float*)(ws + off);    off += (size_t)BB * SL * 4;
    int*      tkidx    = (int*)(ws + off);      off += (size_t)BB * KK * 4;
    float*    tkprob   = (float*)(ws + off);    off += (size_t)BB * KK * 4;
    off = (off + 255) & ~(size_t)255;
    _Float16* qkvh     = (_Float16*)(ws + off); off += QKVN * 2;   // reused as g1
    _Float16* Qh       = (_Float16*)(ws + off); off += HN * 2;
    _Float16* Kh       = (_Float16*)(ws + off); off += HN * 2;
    _Float16* Vh       = (_Float16*)(ws + off); off += HN * 2;
    _Float16* WqkvH    = (_Float16*)(ws + off);
    _Float16* woH   = WqkvH + (size_t)NL * 3 * DD * DD;
    _Float16* gateH = woH   + (size_t)NL * DD * DD;
    _Float16* upH   = gateH + (size_t)NL * FF * DD;
    _Float16* downH = upH   + (size_t)NL * FF * DD;
    _Float16* g1 = qkvh;

    cast4_kernel<<<(NL * 3 * DD * DD / 4 + 255) / 256, 256, 0, stream>>>(Wqkv, WqkvH, NL * 3 * DD * DD / 4);
    cast4_kernel<<<(NL * DD * DD / 4 + 255) / 256, 256, 0, stream>>>(wo_w, woH, NL * DD * DD / 4);
    cast4_kernel<<<(NL * FF * DD / 4 + 255) / 256, 256, 0, stream>>>(gate_w, gateH, NL * FF * DD / 4);
    cast4_kernel<<<(NL * FF * DD / 4 + 255) / 256, 256, 0, stream>>>(up_w, upH, NL * FF * DD / 4);
    cast4_kernel<<<(NL * DD * FF / 4 + 255) / 256, 256, 0, stream>>>(down_w, downH, NL * DD * FF / 4);

    embed_kernel<<<20480, 256, 0, stream>>>(ids, iter, emb, iter_emb, x);

    const int M1 = BB * SL;    // 16384
    const int M2 = BB * KK;    // 13104
    for (int l = 0; l < NL; ++l) {
        rmsnorm_kernel<_Float16><<<4096, 256, 0, stream>>>(x, attn_norm_w + l * DD, h, M1);
        gemm_mfma<0><<<dim3(8, 128), 256, 0, stream>>>(h, WqkvH + (size_t)l * 3 * DD * DD,
                                                       qkvh, nullptr, M1, 3 * DD, DD, nullptr, nullptr);
        prep_kernel<<<dim3(SL / 64, NH, BB), 256, 0, stream>>>(qkvh, Qh, Kh, Vh);
        attn_mfma<<<dim3(SL / 128, NH, BB), 256, 0, stream>>>(Qh, Kh, Vh, attn_out);
        gemm_mfma<1><<<dim3(3, 128), 256, 0, stream>>>(attn_out, woH + (size_t)l * DD * DD,
                                                       nullptr, x, M1, DD, DD, nullptr, nullptr);
        router_kernel<<<4096, 256, 0, stream>>>(x, router_w + l * DD, probs, M1);
        topk_kernel<<<BB, 1024, 0, stream>>>(probs, tkidx, tkprob);
        gather_rmsnorm_kernel<<<3276, 256, 0, stream>>>(x, tkidx, mlp_norm_w + l * DD, h, M2);
        gemm_gateup<<<dim3(7, 103), 256, 0, stream>>>(h, gateH + (size_t)l * FF * DD,
                                                      upH + (size_t)l * FF * DD, g1, M2, FF, DD);
        gemm_mfma<2><<<dim3(3, 103), 256, 0, stream>>>(g1, downH + (size_t)l * DD * FF,
                                                       nullptr, x, M2, DD, FF, tkidx, tkprob);
    }
    rmsnorm_kernel<float><<<4096, 256, 0, stream>>>(x, final_norm_w, out, M1);
}